// Round 9
// baseline (351.143 us; speedup 1.0000x reference)
//
#include <hip/hip_runtime.h>
#include <type_traits>

// MD-GRU (4-direction 2D GRU), block-resident wavefront scan, v9.
// 512 blocks x 512 threads (8 waves): 1 dir x 1 batch elem per block.
// U^T is STREAMED from L2 each K-step (768 KB, XCD-L2-resident; loop-invariant
// base + imm offsets) instead of register-resident -> VGPR <= 128 ->
// 4 waves/SIMD, 2 blocks/CU (v8 was stuck at 23% occupancy with register-U).
// GRU mix term lives in REGISTERS (h_left = own prev, h_top = prev r-1 or
// 2x __shfl across 16 lanes) -> no hmix buffer. hbf: [buf][cell(32)][272B]
// stride-272 rows (2-way bank aliasing = free), cs*64 stays an immediate.
// Workspace: [0,786432) U^T bf16 [a][n(384)][kk(256)]; then finals f32 [a][b][hh].

#define B_ 128
#define N_ 32
#define H_ 128
#define TH 384
#define KK 256

#define SLOT 272           // bytes per cell row (256 data + 16 pad)
#define HBUF 8704          // 32 * 272
#define NL2E -1.44269504088896f

typedef short bf16x8 __attribute__((ext_vector_type(8)));
typedef float f32x4 __attribute__((ext_vector_type(4)));

__device__ inline ushort f2bf(float f) {  // round-to-nearest (ties away)
    return (ushort)((__float_as_uint(f) + 0x8000u) >> 16);
}
__device__ inline ushort f2bf_rne(float f) {
    unsigned u = __float_as_uint(f);
    return (ushort)((u + 0x7FFFu + ((u >> 16) & 1u)) >> 16);
}

// ---- U1,U2 (f32, [a][k][n]) -> U^T bf16 [a][n][kk], kk = mat*128 + k ----
__global__ void conv_u(const float* __restrict__ U1, const float* __restrict__ U2,
                       ushort* __restrict__ ubf) {
    __shared__ float t[32][33];
    int bx = blockIdx.x;
    int amat = bx / 48, tile = bx % 48;
    int kt = tile / 12, ntl = tile % 12;
    int a = amat >> 1, mat = amat & 1;
    int kk0 = kt * 32, n0 = ntl * 32;
    int tx = threadIdx.x, ty = threadIdx.y;
    const float* U = mat ? U2 : U1;
#pragma unroll
    for (int r = 0; r < 4; r++)
        t[ty + r * 8][tx] = U[(a * H_ + kk0 + ty + r * 8) * TH + n0 + tx];
    __syncthreads();
#pragma unroll
    for (int r = 0; r < 4; r++) {
        int n = n0 + ty + r * 8;
        int kkl = kk0 + tx;
        ubf[(a * TH + n) * KK + mat * H_ + kkl] = f2bf_rne(t[tx][ty + r * 8]);
    }
}

// ---- persistent block-resident scan: 512 blocks x 512 threads (8 waves) ----
__global__ __launch_bounds__(512, 4) void scan_all(
    const float* __restrict__ x, const float* __restrict__ Wx,
    const float* __restrict__ bvec, const ushort* __restrict__ ubf,
    float* __restrict__ finals) {

    // hbf: h bf16 double buffer, [buf(2)][cell(32)][128 bf16 + 8 pad].
    // cell i's h at row i. Top pred of cell i = row i-1 (i=0 -> zero frag),
    // left pred = row i.
    __shared__ __align__(16) char hbf_c[2 * HBUF];   // 17408 B
    __shared__ __align__(16) float xd[63 * 32];      // 8064 B, diag-major x

    int bx = blockIdx.x;
    int a = bx >> 7, b = bx & 127;
    int tid = threadIdx.x;
    int lane = tid & 63, wn = tid >> 6;  // wn in [0,8): 16 hh-cols x 3 gates
    int l16 = lane & 15, lg = lane >> 4;

    for (int idx = tid; idx < (2 * HBUF) / 4; idx += 512) ((unsigned*)hbf_c)[idx] = 0u;
    for (int idx = tid; idx < 63 * 32; idx += 512) xd[idx] = 0.0f;
    __syncthreads();
    const float* xg = x + b * (N_ * N_);
    for (int cell = tid; cell < 1024; cell += 512) {
        int i = cell >> 5, j = cell & 31;
        int ri = (a & 1) ? (31 - i) : i;
        int cj = (a & 2) ? (31 - j) : j;
        xd[(i + j) * 32 + i] = xg[ri * 32 + cj];
    }

    // B stream bases (L2-resident U^T): col n = p*128 + wn*16 + l16
    const ushort* ub = ubf + a * (TH * KK);
    const ushort* bp0 = ub + (wn * 16 + l16) * KK + lg * 8;
    const ushort* bp1 = bp0 + H_ * KK;
    const ushort* bp2 = bp1 + H_ * KK;

    int hh = wn * 16 + l16;
    float wxp[3], bsp[3];
    {
        float wr = Wx[a * TH + hh], br = bvec[a * TH + hh];
        float wz = Wx[a * TH + H_ + hh], bz = bvec[a * TH + H_ + hh];
        float wq = Wx[a * TH + 2 * H_ + hh], bq = bvec[a * TH + 2 * H_ + hh];
        wxp[0] = wr * NL2E; bsp[0] = br * NL2E;
        wxp[1] = wz * NL2E; bsp[1] = bz * NL2E;
        wxp[2] = wq;        bsp[2] = bq;
    }

    // loop-invariant LDS addresses
    int sT0 = (l16 == 0) ? 0 : (l16 - 1);
    bool zeroA = (l16 == 0);
    int aT0 = sT0 * SLOT + lg * 16;
    int aL0 = l16 * SLOT + lg * 16;
    int aT1 = (15 + l16) * SLOT + lg * 16;
    int aL1 = aT1 + SLOT;
    int wb0 = (lg * 4) * SLOT + hh * 2;
    int wb1 = wb0 + 16 * SLOT;

    const char* xdp = (const char*)xd + lg * 16;

    __syncthreads();

    float hp0[4] = {0.0f, 0.0f, 0.0f, 0.0f};  // mt=0 prev h (rows lg*4+r)
    float hp1[4] = {0.0f, 0.0f, 0.0f, 0.0f};  // mt=1 prev h
    const bf16x8 zf = {0, 0, 0, 0, 0, 0, 0, 0};

    auto step = [&](int d, const char* xp, auto WRC) {
        constexpr int WRB = decltype(WRC)::value;
        constexpr int RDB = WRB ^ 1;
        const char* hbr = hbf_c + RDB * HBUF;
        char* hbw = hbf_c + WRB * HBUF;

        f32x4 xv0 = *(const f32x4*)(xp);
        f32x4 xv1 = *(const f32x4*)(xp + 64);

        f32x4 acc[2][3];
#pragma unroll
        for (int mt = 0; mt < 2; mt++)
#pragma unroll
            for (int p = 0; p < 3; p++)
                acc[mt][p] = (f32x4){0.0f, 0.0f, 0.0f, 0.0f};

#pragma unroll
        for (int ks = 0; ks < 8; ks++) {
            const int cs = ks & 3;
            bf16x8 b0 = *(const bf16x8*)(bp0 + ks * 32);
            bf16x8 b1 = *(const bf16x8*)(bp1 + ks * 32);
            bf16x8 b2 = *(const bf16x8*)(bp2 + ks * 32);
            bf16x8 a0, a1;
            if (ks < 4) {
                a0 = *(const bf16x8*)(hbr + aT0 + cs * 64);
                a0 = zeroA ? zf : a0;
                a1 = *(const bf16x8*)(hbr + aT1 + cs * 64);
            } else {
                a0 = *(const bf16x8*)(hbr + aL0 + cs * 64);
                a1 = *(const bf16x8*)(hbr + aL1 + cs * 64);
            }
            acc[0][0] = __builtin_amdgcn_mfma_f32_16x16x32_bf16(a0, b0, acc[0][0], 0, 0, 0);
            acc[0][1] = __builtin_amdgcn_mfma_f32_16x16x32_bf16(a0, b1, acc[0][1], 0, 0, 0);
            acc[0][2] = __builtin_amdgcn_mfma_f32_16x16x32_bf16(a0, b2, acc[0][2], 0, 0, 0);
            acc[1][0] = __builtin_amdgcn_mfma_f32_16x16x32_bf16(a1, b0, acc[1][0], 0, 0, 0);
            acc[1][1] = __builtin_amdgcn_mfma_f32_16x16x32_bf16(a1, b1, acc[1][1], 0, 0, 0);
            acc[1][2] = __builtin_amdgcn_mfma_f32_16x16x32_bf16(a1, b2, acc[1][2], 0, 0, 0);
        }

        // cross-lane previous-h for r=0 rows
        float sA = __shfl(hp0[3], (lane - 16) & 63, 64);
        float sB = __shfl(hp1[3], (lane - 16) & 63, 64);

        // epilogue per mt (wave-uniform guards: tile activity window)
#pragma unroll
        for (int mt = 0; mt < 2; mt++) {
            if (d >= mt * 16 && d <= mt * 16 + 46) {
                float* hp = mt ? hp1 : hp0;
                float top0 = mt ? (lg ? sB : sA) : (lg ? sA : 0.0f);
                int dm = d - mt * 16 - lg * 4;
                f32x4 xv = mt ? xv1 : xv0;
                float hv[4];
#pragma unroll
                for (int r = 0; r < 4; r++) {
                    float xb = xv[r];
                    float htop = r ? hp[r - 1] : top0;
                    float hlft = hp[r];
                    float Gr = acc[mt][0][r];
                    float Gz = acc[mt][1][r];
                    float Gn = acc[mt][2][r];
                    float ar = __builtin_fmaf(Gr, NL2E, __builtin_fmaf(xb, wxp[0], bsp[0]));
                    float rg = __builtin_amdgcn_rcpf(1.0f + __builtin_amdgcn_exp2f(ar));
                    float az = __builtin_fmaf(Gz, NL2E, __builtin_fmaf(xb, wxp[1], bsp[1]));
                    float zg = __builtin_amdgcn_rcpf(1.0f + __builtin_amdgcn_exp2f(az));
                    float vn = __builtin_fmaf(rg, Gn, __builtin_fmaf(xb, wxp[2], bsp[2]));
                    float en = __builtin_amdgcn_exp2f(vn * (2.0f * NL2E));
                    float ng = __builtin_fmaf(2.0f, __builtin_amdgcn_rcpf(1.0f + en), -1.0f);
                    float hs = htop + hlft;
                    hv[r] = __builtin_fmaf(-zg, __builtin_fmaf(-0.5f, hs, ng), ng);
                }
                int wb = mt ? wb1 : wb0;
#pragma unroll
                for (int r = 0; r < 4; r++)
                    *(ushort*)(hbw + wb + r * SLOT) = f2bf(hv[r]);
#pragma unroll
                for (int r = 0; r < 4; r++)
                    hp[r] = (r <= dm) ? hv[r] : hp[r];
            }
        }
        __syncthreads();
    };

    for (int d = 0; d < 62; d += 2) {
        step(d, xdp, std::integral_constant<int, 0>{});
        step(d + 1, xdp + 128, std::integral_constant<int, 1>{});
        xdp += 256;
    }
    step(62, xdp, std::integral_constant<int, 0>{});

    // terminal corner: row 31 = mt1, lg==3, r=3
    if (lg == 3) finals[(a * B_ + b) * H_ + hh] = hp1[3];
}

// ---- final: concat 4 terminal h's -> logits -> log_softmax ----
__global__ void classify(const float* __restrict__ fin, const float* __restrict__ Wo,
                         const float* __restrict__ bo, float* __restrict__ out) {
    int b = blockIdx.x;
    int lane = threadIdx.x;  // 64
    float acc[10];
#pragma unroll
    for (int o = 0; o < 10; o++) acc[o] = 0.0f;
#pragma unroll
    for (int kkx = 0; kkx < 8; kkx++) {
        int k = kkx * 64 + lane;
        int a = k >> 7, hh = k & 127;
        float fh = fin[(a * B_ + b) * H_ + hh];
#pragma unroll
        for (int o = 0; o < 10; o++) acc[o] += fh * Wo[k * 10 + o];
    }
    float logits[10];
#pragma unroll
    for (int o = 0; o < 10; o++) {
        float v = acc[o];
#pragma unroll
        for (int off = 32; off; off >>= 1) v += __shfl_xor(v, off, 64);
        logits[o] = v + bo[o];
    }
    float m = logits[0];
#pragma unroll
    for (int o = 1; o < 10; o++) m = fmaxf(m, logits[o]);
    float s = 0.0f;
#pragma unroll
    for (int o = 0; o < 10; o++) s += __expf(logits[o] - m);
    float lse = m + __logf(s);
    if (lane == 0) {
#pragma unroll
        for (int o = 0; o < 10; o++) out[b * 10 + o] = logits[o] - lse;
    }
}

extern "C" void kernel_launch(void* const* d_in, const int* in_sizes, int n_in,
                              void* d_out, int out_size, void* d_ws, size_t ws_size,
                              hipStream_t stream) {
    const float* x = (const float*)d_in[0];
    const float* Wx = (const float*)d_in[1];
    const float* U1 = (const float*)d_in[2];
    const float* U2 = (const float*)d_in[3];
    const float* bv = (const float*)d_in[4];
    const float* Wo = (const float*)d_in[5];
    const float* bo = (const float*)d_in[6];
    float* out = (float*)d_out;

    char* ws = (char*)d_ws;
    ushort* ubf = (ushort*)ws;                // 786432 B
    float* finals = (float*)(ws + 786432);    // 4*128*128*4 = 256 KB

    hipLaunchKernelGGL(conv_u, dim3(384), dim3(32, 8), 0, stream, U1, U2, ubf);
    hipLaunchKernelGGL(scan_all, dim3(512), dim3(512), 0, stream, x, Wx, bv, ubf, finals);
    hipLaunchKernelGGL(classify, dim3(128), dim3(64), 0, stream, finals, Wo, bo, out);
}

// Round 10
// 174.965 us; speedup vs baseline: 2.0069x; 2.0069x over previous
//
#include <hip/hip_runtime.h>
#include <type_traits>

// MD-GRU (4-direction 2D GRU), block-resident wavefront scan, v10.
// = v8 structure (256 blocks x 8 waves, Bc=2, register-resident U^T,
// fixed-row indexing, loop-invariant addresses) with:
//  - hmix deleted: GRU mix term in registers hp[mt][p2][bl]; h_top via
//    hp[mt][0] (p2=1) or __shfl(lane-16) of neighbor p2=1 (v9-proven).
//  - pair-level guards only (pair01: d<=47, pair23: d>=16); no per-lane
//    masks (zero-propagation: x=0,b=0,zero slots => hv==0 for idle rows;
//    post-finish garbage provably unconsumed; hbf double-buffered).
//  - acc zero-init via shared z4 C-in; s_setprio around MFMA cluster.
// v9 lesson: B streamed from L2 costs ~6.3 GB/scan -> must stay in regs.
// Workspace: [0,786432) U^T bf16 [a][n(384)][kk(256)]; then finals f32 [a][b][hh].

#define B_ 128
#define N_ 32
#define H_ 128
#define TH 384
#define KK 256

#define HBF_PLANE 4224   // 33 slots * 128 B (one 32-k plane)
#define HBF_BUF   16896  // 4 planes
#define XD_STEP   256    // 32 rows * float2

typedef short bf16x8 __attribute__((ext_vector_type(8)));
typedef float f32x4 __attribute__((ext_vector_type(4)));

__device__ inline ushort f2bf(float f) {  // round-to-nearest (ties away)
    return (ushort)((__float_as_uint(f) + 0x8000u) >> 16);
}
__device__ inline ushort f2bf_rne(float f) {
    unsigned u = __float_as_uint(f);
    return (ushort)((u + 0x7FFFu + ((u >> 16) & 1u)) >> 16);
}

#define NL2E -1.44269504088896f

// ---- U1,U2 (f32, [a][k][n]) -> U^T bf16 [a][n][kk], kk = mat*128 + k ----
__global__ void conv_u(const float* __restrict__ U1, const float* __restrict__ U2,
                       ushort* __restrict__ ubf) {
    __shared__ float t[32][33];
    int bx = blockIdx.x;
    int amat = bx / 48, tile = bx % 48;
    int kt = tile / 12, ntl = tile % 12;
    int a = amat >> 1, mat = amat & 1;
    int kk0 = kt * 32, n0 = ntl * 32;
    int tx = threadIdx.x, ty = threadIdx.y;
    const float* U = mat ? U2 : U1;
#pragma unroll
    for (int r = 0; r < 4; r++)
        t[ty + r * 8][tx] = U[(a * H_ + kk0 + ty + r * 8) * TH + n0 + tx];
    __syncthreads();
#pragma unroll
    for (int r = 0; r < 4; r++) {
        int n = n0 + ty + r * 8;
        int kkl = kk0 + tx;
        ubf[(a * TH + n) * KK + mat * H_ + kkl] = f2bf_rne(t[tx][ty + r * 8]);
    }
}

// ---- persistent block-resident scan: 256 blocks x 512 threads (8 waves) ----
__global__ __launch_bounds__(512, 2) void scan_all(
    const float* __restrict__ x, const float* __restrict__ Wx,
    const float* __restrict__ bvec, const ushort* __restrict__ ubf,
    float* __restrict__ finals) {

    __shared__ __align__(16) char hbf_c[2 * HBF_BUF];    // 33792 B
    __shared__ __align__(16) char xd_c[63 * XD_STEP];    // 16128 B

    int bx = blockIdx.x;
    int a = bx >> 6, chunk = bx & 63;
    int tid = threadIdx.x;
    int lane = tid & 63, wn = tid >> 6;  // wn in [0,8): 16 hh-cols x 3 gates
    int l16 = lane & 15, lg = lane >> 4;

    for (int idx = tid; idx < (2 * HBF_BUF) / 4; idx += 512) ((unsigned*)hbf_c)[idx] = 0u;
    for (int idx = tid; idx < (63 * XD_STEP) / 4; idx += 512) ((unsigned*)xd_c)[idx] = 0u;
    __syncthreads();

    // x -> diagonal-major LDS: xd[d][i] = {x_b0(i,d-i), x_b1(i,d-i)}
    const float* xg = x + (chunk * 2) * (N_ * N_);
    for (int cell = tid; cell < 1024; cell += 512) {
        int i = cell >> 5, j = cell & 31;
        int ri = (a & 1) ? (31 - i) : i;
        int cj = (a & 2) ? (31 - j) : j;
        float v0 = xg[ri * 32 + cj];
        float v1 = xg[1024 + ri * 32 + cj];
        *(float2*)(xd_c + (i + j) * XD_STEP + i * 8) = make_float2(v0, v1);
    }

    // persistent U^T fragments (96 regs; unified VGPR/AGPR file)
    const ushort* ub = ubf + a * (TH * KK);
    bf16x8 Bf[3][8];
#pragma unroll
    for (int p = 0; p < 3; p++) {
        int n = p * H_ + wn * 16 + l16;
#pragma unroll
        for (int ks = 0; ks < 8; ks++) {
            Bf[p][ks] = *(const bf16x8*)(ub + n * KK + ks * 32 + lg * 8);
            asm volatile("" : "+v"(Bf[p][ks]));
        }
    }

    int hh = wn * 16 + l16;
    float wxp[3], bsp[3];
    {
        float wr = Wx[a * TH + hh], br = bvec[a * TH + hh];
        float wz = Wx[a * TH + H_ + hh], bz = bvec[a * TH + H_ + hh];
        float wq = Wx[a * TH + 2 * H_ + hh], bq = bvec[a * TH + 2 * H_ + hh];
        wxp[0] = wr * NL2E; bsp[0] = br * NL2E;
        wxp[1] = wz * NL2E; bsp[1] = bz * NL2E;
        wxp[2] = wq;        bsp[2] = bq;
    }

    // loop-invariant LDS addresses (A-row m = mt*16+l16 -> cell m>>1, bl m&1)
    int ciA = l16 >> 1, blA = l16 & 1;
    int aT[4], aL[4], wb[4][2][2];
#pragma unroll
    for (int mt = 0; mt < 4; mt++) {
        int st = mt * 8 + ciA;  // top slot
        aT[mt] = st * 128 + ((blA * 64 + lg * 16) ^ ((st & 7) << 4));
        int sl = st + 1;        // left slot
        aL[mt] = sl * 128 + ((blA * 64 + lg * 16) ^ ((sl & 7) << 4));
#pragma unroll
        for (int p2 = 0; p2 < 2; p2++) {
            int sw = mt * 8 + lg * 2 + p2 + 1;  // write slot (row+1)
#pragma unroll
            for (int bl = 0; bl < 2; bl++)
                wb[mt][p2][bl] = (hh >> 5) * HBF_PLANE + sw * 128 +
                                 ((bl * 64 + (hh & 31) * 2) ^ ((sw & 7) << 4));
        }
    }

    const char* xdp = xd_c + lg * 16;
    __syncthreads();

    float hp[4][2][2];  // [mt][p2][bl] latest h of row mt*8+lg*2+p2
#pragma unroll
    for (int mt = 0; mt < 4; mt++)
#pragma unroll
        for (int p2 = 0; p2 < 2; p2++)
#pragma unroll
            for (int bl = 0; bl < 2; bl++) hp[mt][p2][bl] = 0.0f;

    int slsrc = (lane - 16) & 63;

    auto step = [&](int d, auto WRC) {
        constexpr int WRB = decltype(WRC)::value;
        constexpr int RDB = WRB ^ 1;
        const char* hbr = hbf_c + RDB * HBF_BUF;
        char* hbw = hbf_c + WRB * HBF_BUF;

        // neighbor p2=1 prev-h, pulled before any update this step
        float sh[4][2];
#pragma unroll
        for (int mt = 0; mt < 4; mt++)
#pragma unroll
            for (int bl = 0; bl < 2; bl++)
                sh[mt][bl] = __shfl(hp[mt][1][bl], slsrc, 64);

        bool g01 = (d <= 47), g23 = (d >= 16);
        f32x4 acc[4][3];
        const f32x4 z4 = {0.0f, 0.0f, 0.0f, 0.0f};

        __builtin_amdgcn_s_setprio(1);
#pragma unroll
        for (int mt = 0; mt < 4; mt++) {
            bool g = (mt < 2) ? g01 : g23;
            if (g) {
                bf16x8 af[4];
#pragma unroll
                for (int ks = 0; ks < 4; ks++)
                    af[ks] = *(const bf16x8*)(hbr + ks * HBF_PLANE + aT[mt]);
#pragma unroll
                for (int ks = 0; ks < 4; ks++)
#pragma unroll
                    for (int p = 0; p < 3; p++)
                        acc[mt][p] = __builtin_amdgcn_mfma_f32_16x16x32_bf16(
                            af[ks], Bf[p][ks], (ks == 0) ? z4 : acc[mt][p], 0, 0, 0);
#pragma unroll
                for (int ks = 0; ks < 4; ks++)
                    af[ks] = *(const bf16x8*)(hbr + ks * HBF_PLANE + aL[mt]);
#pragma unroll
                for (int ks = 0; ks < 4; ks++)
#pragma unroll
                    for (int p = 0; p < 3; p++)
                        acc[mt][p] = __builtin_amdgcn_mfma_f32_16x16x32_bf16(
                            af[ks], Bf[p][ks + 4], acc[mt][p], 0, 0, 0);
            }
        }
        __builtin_amdgcn_s_setprio(0);

        // epilogue: gates + mix from hp registers, write bf16 h
#pragma unroll
        for (int mt = 0; mt < 4; mt++) {
            bool g = (mt < 2) ? g01 : g23;
            if (g) {
                f32x4 xv = *(const f32x4*)(xdp + WRB * 256 + mt * 64);
                float hv[2][2];
#pragma unroll
                for (int p2 = 0; p2 < 2; p2++)
#pragma unroll
                    for (int bl = 0; bl < 2; bl++) {
                        int r = p2 * 2 + bl;
                        float xb = xv[r];
                        float htop = p2 ? hp[mt][0][bl]
                                        : (lg ? sh[mt][bl]
                                              : (mt ? sh[mt - 1][bl] : 0.0f));
                        float hlft = hp[mt][p2][bl];
                        float Gr = acc[mt][0][r];
                        float Gz = acc[mt][1][r];
                        float Gn = acc[mt][2][r];
                        float ar = __builtin_fmaf(Gr, NL2E, __builtin_fmaf(xb, wxp[0], bsp[0]));
                        float rg = __builtin_amdgcn_rcpf(1.0f + __builtin_amdgcn_exp2f(ar));
                        float az = __builtin_fmaf(Gz, NL2E, __builtin_fmaf(xb, wxp[1], bsp[1]));
                        float zg = __builtin_amdgcn_rcpf(1.0f + __builtin_amdgcn_exp2f(az));
                        float vn = __builtin_fmaf(rg, Gn, __builtin_fmaf(xb, wxp[2], bsp[2]));
                        float en = __builtin_amdgcn_exp2f(vn * (2.0f * NL2E));
                        float ng = __builtin_fmaf(2.0f, __builtin_amdgcn_rcpf(1.0f + en), -1.0f);
                        float hs = htop + hlft;
                        hv[p2][bl] = __builtin_fmaf(-zg, __builtin_fmaf(-0.5f, hs, ng), ng);
                    }
#pragma unroll
                for (int p2 = 0; p2 < 2; p2++)
#pragma unroll
                    for (int bl = 0; bl < 2; bl++) {
                        *(ushort*)(hbw + wb[mt][p2][bl]) = f2bf(hv[p2][bl]);
                        hp[mt][p2][bl] = hv[p2][bl];
                    }
            }
        }
        __syncthreads();
    };

    for (int d = 0; d < 62; d += 2) {
        step(d, std::integral_constant<int, 0>{});
        step(d + 1, std::integral_constant<int, 1>{});
        xdp += 512;
    }
    step(62, std::integral_constant<int, 0>{});

    // terminal corner: row 31 = mt3/p2=1 on lg==3 lanes
    if (lg == 3) {
        finals[(a * B_ + chunk * 2) * H_ + hh] = hp[3][1][0];
        finals[(a * B_ + chunk * 2 + 1) * H_ + hh] = hp[3][1][1];
    }
}

// ---- final: concat 4 terminal h's -> logits -> log_softmax ----
__global__ void classify(const float* __restrict__ fin, const float* __restrict__ Wo,
                         const float* __restrict__ bo, float* __restrict__ out) {
    int b = blockIdx.x;
    int lane = threadIdx.x;  // 64
    float acc[10];
#pragma unroll
    for (int o = 0; o < 10; o++) acc[o] = 0.0f;
#pragma unroll
    for (int kkx = 0; kkx < 8; kkx++) {
        int k = kkx * 64 + lane;
        int a = k >> 7, hh = k & 127;
        float fh = fin[(a * B_ + b) * H_ + hh];
#pragma unroll
        for (int o = 0; o < 10; o++) acc[o] += fh * Wo[k * 10 + o];
    }
    float logits[10];
#pragma unroll
    for (int o = 0; o < 10; o++) {
        float v = acc[o];
#pragma unroll
        for (int off = 32; off; off >>= 1) v += __shfl_xor(v, off, 64);
        logits[o] = v + bo[o];
    }
    float m = logits[0];
#pragma unroll
    for (int o = 1; o < 10; o++) m = fmaxf(m, logits[o]);
    float s = 0.0f;
#pragma unroll
    for (int o = 0; o < 10; o++) s += __expf(logits[o] - m);
    float lse = m + __logf(s);
    if (lane == 0) {
#pragma unroll
        for (int o = 0; o < 10; o++) out[b * 10 + o] = logits[o] - lse;
    }
}

extern "C" void kernel_launch(void* const* d_in, const int* in_sizes, int n_in,
                              void* d_out, int out_size, void* d_ws, size_t ws_size,
                              hipStream_t stream) {
    const float* x = (const float*)d_in[0];
    const float* Wx = (const float*)d_in[1];
    const float* U1 = (const float*)d_in[2];
    const float* U2 = (const float*)d_in[3];
    const float* bv = (const float*)d_in[4];
    const float* Wo = (const float*)d_in[5];
    const float* bo = (const float*)d_in[6];
    float* out = (float*)d_out;

    char* ws = (char*)d_ws;
    ushort* ubf = (ushort*)ws;                // 786432 B
    float* finals = (float*)(ws + 786432);    // 4*128*128*4 = 256 KB

    hipLaunchKernelGGL(conv_u, dim3(384), dim3(32, 8), 0, stream, U1, U2, ubf);
    hipLaunchKernelGGL(scan_all, dim3(256), dim3(512), 0, stream, x, Wx, bv, ubf, finals);
    hipLaunchKernelGGL(classify, dim3(128), dim3(64), 0, stream, finals, Wo, bo, out);
}

// Round 11
// 153.354 us; speedup vs baseline: 2.2897x; 1.1409x over previous
//
#include <hip/hip_runtime.h>
#include <type_traits>

// MD-GRU (4-direction 2D GRU), block-resident wavefront scan, v11.
// = v10 (register-resident U^T, register mix term, conflict-free LDS,
// fixed-row indexing) with the v10 regression reverted:
//  - per-mt guard windows restored (tile mt active d in [mt*8, mt*8+38];
//    156 tile-steps vs v10's pair-guard 190 -> -22% work). Correctness
//    without per-lane masks: pre-start rows are exact zero (x=0 + zero
//    slots + zero Bf => hv==0); post-finish garbage lands only in slots
//    whose consumers are already finished (producer window == consumer
//    need window); terminal hp[3][1] written at d=62 (in-window).
//  - s_setprio removed (lockstep 8-wave block: m190 regime, hurts).
//  - xv loads hoisted ahead of the MFMA cluster.
// Workspace: [0,786432) U^T bf16 [a][n(384)][kk(256)]; then finals f32 [a][b][hh].

#define B_ 128
#define N_ 32
#define H_ 128
#define TH 384
#define KK 256

#define HBF_PLANE 4224   // 33 slots * 128 B (one 32-k plane)
#define HBF_BUF   16896  // 4 planes
#define XD_STEP   256    // 32 rows * float2

typedef short bf16x8 __attribute__((ext_vector_type(8)));
typedef float f32x4 __attribute__((ext_vector_type(4)));

__device__ inline ushort f2bf(float f) {  // round-to-nearest (ties away)
    return (ushort)((__float_as_uint(f) + 0x8000u) >> 16);
}
__device__ inline ushort f2bf_rne(float f) {
    unsigned u = __float_as_uint(f);
    return (ushort)((u + 0x7FFFu + ((u >> 16) & 1u)) >> 16);
}

#define NL2E -1.44269504088896f

// ---- U1,U2 (f32, [a][k][n]) -> U^T bf16 [a][n][kk], kk = mat*128 + k ----
__global__ void conv_u(const float* __restrict__ U1, const float* __restrict__ U2,
                       ushort* __restrict__ ubf) {
    __shared__ float t[32][33];
    int bx = blockIdx.x;
    int amat = bx / 48, tile = bx % 48;
    int kt = tile / 12, ntl = tile % 12;
    int a = amat >> 1, mat = amat & 1;
    int kk0 = kt * 32, n0 = ntl * 32;
    int tx = threadIdx.x, ty = threadIdx.y;
    const float* U = mat ? U2 : U1;
#pragma unroll
    for (int r = 0; r < 4; r++)
        t[ty + r * 8][tx] = U[(a * H_ + kk0 + ty + r * 8) * TH + n0 + tx];
    __syncthreads();
#pragma unroll
    for (int r = 0; r < 4; r++) {
        int n = n0 + ty + r * 8;
        int kkl = kk0 + tx;
        ubf[(a * TH + n) * KK + mat * H_ + kkl] = f2bf_rne(t[tx][ty + r * 8]);
    }
}

// ---- persistent block-resident scan: 256 blocks x 512 threads (8 waves) ----
__global__ __launch_bounds__(512, 2) void scan_all(
    const float* __restrict__ x, const float* __restrict__ Wx,
    const float* __restrict__ bvec, const ushort* __restrict__ ubf,
    float* __restrict__ finals) {

    __shared__ __align__(16) char hbf_c[2 * HBF_BUF];    // 33792 B
    __shared__ __align__(16) char xd_c[63 * XD_STEP];    // 16128 B

    int bx = blockIdx.x;
    int a = bx >> 6, chunk = bx & 63;
    int tid = threadIdx.x;
    int lane = tid & 63, wn = tid >> 6;  // wn in [0,8): 16 hh-cols x 3 gates
    int l16 = lane & 15, lg = lane >> 4;

    for (int idx = tid; idx < (2 * HBF_BUF) / 4; idx += 512) ((unsigned*)hbf_c)[idx] = 0u;
    for (int idx = tid; idx < (63 * XD_STEP) / 4; idx += 512) ((unsigned*)xd_c)[idx] = 0u;
    __syncthreads();

    // x -> diagonal-major LDS: xd[d][i] = {x_b0(i,d-i), x_b1(i,d-i)}
    const float* xg = x + (chunk * 2) * (N_ * N_);
    for (int cell = tid; cell < 1024; cell += 512) {
        int i = cell >> 5, j = cell & 31;
        int ri = (a & 1) ? (31 - i) : i;
        int cj = (a & 2) ? (31 - j) : j;
        float v0 = xg[ri * 32 + cj];
        float v1 = xg[1024 + ri * 32 + cj];
        *(float2*)(xd_c + (i + j) * XD_STEP + i * 8) = make_float2(v0, v1);
    }

    // persistent U^T fragments (96 regs; unified VGPR/AGPR file)
    const ushort* ub = ubf + a * (TH * KK);
    bf16x8 Bf[3][8];
#pragma unroll
    for (int p = 0; p < 3; p++) {
        int n = p * H_ + wn * 16 + l16;
#pragma unroll
        for (int ks = 0; ks < 8; ks++) {
            Bf[p][ks] = *(const bf16x8*)(ub + n * KK + ks * 32 + lg * 8);
            asm volatile("" : "+v"(Bf[p][ks]));
        }
    }

    int hh = wn * 16 + l16;
    float wxp[3], bsp[3];
    {
        float wr = Wx[a * TH + hh], br = bvec[a * TH + hh];
        float wz = Wx[a * TH + H_ + hh], bz = bvec[a * TH + H_ + hh];
        float wq = Wx[a * TH + 2 * H_ + hh], bq = bvec[a * TH + 2 * H_ + hh];
        wxp[0] = wr * NL2E; bsp[0] = br * NL2E;
        wxp[1] = wz * NL2E; bsp[1] = bz * NL2E;
        wxp[2] = wq;        bsp[2] = bq;
    }

    // loop-invariant LDS addresses (A-row m = mt*16+l16 -> cell m>>1, bl m&1)
    int ciA = l16 >> 1, blA = l16 & 1;
    int aT[4], aL[4], wb[4][2][2];
#pragma unroll
    for (int mt = 0; mt < 4; mt++) {
        int st = mt * 8 + ciA;  // top slot
        aT[mt] = st * 128 + ((blA * 64 + lg * 16) ^ ((st & 7) << 4));
        int sl = st + 1;        // left slot
        aL[mt] = sl * 128 + ((blA * 64 + lg * 16) ^ ((sl & 7) << 4));
#pragma unroll
        for (int p2 = 0; p2 < 2; p2++) {
            int sw = mt * 8 + lg * 2 + p2 + 1;  // write slot (row+1)
#pragma unroll
            for (int bl = 0; bl < 2; bl++)
                wb[mt][p2][bl] = (hh >> 5) * HBF_PLANE + sw * 128 +
                                 ((bl * 64 + (hh & 31) * 2) ^ ((sw & 7) << 4));
        }
    }

    const char* xdp = xd_c + lg * 16;
    __syncthreads();

    float hp[4][2][2];  // [mt][p2][bl] latest h of row mt*8+lg*2+p2
#pragma unroll
    for (int mt = 0; mt < 4; mt++)
#pragma unroll
        for (int p2 = 0; p2 < 2; p2++)
#pragma unroll
            for (int bl = 0; bl < 2; bl++) hp[mt][p2][bl] = 0.0f;

    int slsrc = (lane - 16) & 63;

    auto step = [&](int d, auto WRC) {
        constexpr int WRB = decltype(WRC)::value;
        constexpr int RDB = WRB ^ 1;
        const char* hbr = hbf_c + RDB * HBF_BUF;
        char* hbw = hbf_c + WRB * HBF_BUF;

        // neighbor p2=1 prev-h, pulled before any update this step
        float sh[4][2];
#pragma unroll
        for (int mt = 0; mt < 4; mt++)
#pragma unroll
            for (int bl = 0; bl < 2; bl++)
                sh[mt][bl] = __shfl(hp[mt][1][bl], slsrc, 64);

        bool gm[4];
        f32x4 xv[4];
#pragma unroll
        for (int mt = 0; mt < 4; mt++) {
            gm[mt] = (d >= mt * 8) && (d <= mt * 8 + 38);  // wave-uniform window
            if (gm[mt]) xv[mt] = *(const f32x4*)(xdp + WRB * 256 + mt * 64);
        }

        f32x4 acc[4][3];
        const f32x4 z4 = {0.0f, 0.0f, 0.0f, 0.0f};

#pragma unroll
        for (int mt = 0; mt < 4; mt++) {
            if (gm[mt]) {
                bf16x8 af[4];
#pragma unroll
                for (int ks = 0; ks < 4; ks++)
                    af[ks] = *(const bf16x8*)(hbr + ks * HBF_PLANE + aT[mt]);
#pragma unroll
                for (int ks = 0; ks < 4; ks++)
#pragma unroll
                    for (int p = 0; p < 3; p++)
                        acc[mt][p] = __builtin_amdgcn_mfma_f32_16x16x32_bf16(
                            af[ks], Bf[p][ks], (ks == 0) ? z4 : acc[mt][p], 0, 0, 0);
#pragma unroll
                for (int ks = 0; ks < 4; ks++)
                    af[ks] = *(const bf16x8*)(hbr + ks * HBF_PLANE + aL[mt]);
#pragma unroll
                for (int ks = 0; ks < 4; ks++)
#pragma unroll
                    for (int p = 0; p < 3; p++)
                        acc[mt][p] = __builtin_amdgcn_mfma_f32_16x16x32_bf16(
                            af[ks], Bf[p][ks + 4], acc[mt][p], 0, 0, 0);
            }
        }

        // epilogue: gates + mix from hp registers, write bf16 h
#pragma unroll
        for (int mt = 0; mt < 4; mt++) {
            if (gm[mt]) {
                float hv[2][2];
#pragma unroll
                for (int p2 = 0; p2 < 2; p2++)
#pragma unroll
                    for (int bl = 0; bl < 2; bl++) {
                        int r = p2 * 2 + bl;
                        float xb = xv[mt][r];
                        float htop = p2 ? hp[mt][0][bl]
                                        : (lg ? sh[mt][bl]
                                              : (mt ? sh[mt - 1][bl] : 0.0f));
                        float hlft = hp[mt][p2][bl];
                        float Gr = acc[mt][0][r];
                        float Gz = acc[mt][1][r];
                        float Gn = acc[mt][2][r];
                        float ar = __builtin_fmaf(Gr, NL2E, __builtin_fmaf(xb, wxp[0], bsp[0]));
                        float rg = __builtin_amdgcn_rcpf(1.0f + __builtin_amdgcn_exp2f(ar));
                        float az = __builtin_fmaf(Gz, NL2E, __builtin_fmaf(xb, wxp[1], bsp[1]));
                        float zg = __builtin_amdgcn_rcpf(1.0f + __builtin_amdgcn_exp2f(az));
                        float vn = __builtin_fmaf(rg, Gn, __builtin_fmaf(xb, wxp[2], bsp[2]));
                        float en = __builtin_amdgcn_exp2f(vn * (2.0f * NL2E));
                        float ng = __builtin_fmaf(2.0f, __builtin_amdgcn_rcpf(1.0f + en), -1.0f);
                        float hs = htop + hlft;
                        hv[p2][bl] = __builtin_fmaf(-zg, __builtin_fmaf(-0.5f, hs, ng), ng);
                    }
#pragma unroll
                for (int p2 = 0; p2 < 2; p2++)
#pragma unroll
                    for (int bl = 0; bl < 2; bl++) {
                        *(ushort*)(hbw + wb[mt][p2][bl]) = f2bf(hv[p2][bl]);
                        hp[mt][p2][bl] = hv[p2][bl];
                    }
            }
        }
        __syncthreads();
    };

    for (int d = 0; d < 62; d += 2) {
        step(d, std::integral_constant<int, 0>{});
        step(d + 1, std::integral_constant<int, 1>{});
        xdp += 512;
    }
    step(62, std::integral_constant<int, 0>{});

    // terminal corner: row 31 = mt3/p2=1 on lg==3 lanes
    if (lg == 3) {
        finals[(a * B_ + chunk * 2) * H_ + hh] = hp[3][1][0];
        finals[(a * B_ + chunk * 2 + 1) * H_ + hh] = hp[3][1][1];
    }
}

// ---- final: concat 4 terminal h's -> logits -> log_softmax ----
__global__ void classify(const float* __restrict__ fin, const float* __restrict__ Wo,
                         const float* __restrict__ bo, float* __restrict__ out) {
    int b = blockIdx.x;
    int lane = threadIdx.x;  // 64
    float acc[10];
#pragma unroll
    for (int o = 0; o < 10; o++) acc[o] = 0.0f;
#pragma unroll
    for (int kkx = 0; kkx < 8; kkx++) {
        int k = kkx * 64 + lane;
        int a = k >> 7, hh = k & 127;
        float fh = fin[(a * B_ + b) * H_ + hh];
#pragma unroll
        for (int o = 0; o < 10; o++) acc[o] += fh * Wo[k * 10 + o];
    }
    float logits[10];
#pragma unroll
    for (int o = 0; o < 10; o++) {
        float v = acc[o];
#pragma unroll
        for (int off = 32; off; off >>= 1) v += __shfl_xor(v, off, 64);
        logits[o] = v + bo[o];
    }
    float m = logits[0];
#pragma unroll
    for (int o = 1; o < 10; o++) m = fmaxf(m, logits[o]);
    float s = 0.0f;
#pragma unroll
    for (int o = 0; o < 10; o++) s += __expf(logits[o] - m);
    float lse = m + __logf(s);
    if (lane == 0) {
#pragma unroll
        for (int o = 0; o < 10; o++) out[b * 10 + o] = logits[o] - lse;
    }
}

extern "C" void kernel_launch(void* const* d_in, const int* in_sizes, int n_in,
                              void* d_out, int out_size, void* d_ws, size_t ws_size,
                              hipStream_t stream) {
    const float* x = (const float*)d_in[0];
    const float* Wx = (const float*)d_in[1];
    const float* U1 = (const float*)d_in[2];
    const float* U2 = (const float*)d_in[3];
    const float* bv = (const float*)d_in[4];
    const float* Wo = (const float*)d_in[5];
    const float* bo = (const float*)d_in[6];
    float* out = (float*)d_out;

    char* ws = (char*)d_ws;
    ushort* ubf = (ushort*)ws;                // 786432 B
    float* finals = (float*)(ws + 786432);    // 4*128*128*4 = 256 KB

    hipLaunchKernelGGL(conv_u, dim3(384), dim3(32, 8), 0, stream, U1, U2, ubf);
    hipLaunchKernelGGL(scan_all, dim3(256), dim3(512), 0, stream, x, Wx, bv, ubf, finals);
    hipLaunchKernelGGL(classify, dim3(128), dim3(64), 0, stream, finals, Wo, bo, out);
}

// Round 12
// 147.444 us; speedup vs baseline: 2.3815x; 1.0401x over previous
//
#include <hip/hip_runtime.h>
#include <type_traits>

// MD-GRU (4-direction 2D GRU), block-resident wavefront scan, v12.
// = v11 (register-resident U^T, register mix term, per-mt guard windows,
// conflict-free LDS, fixed-row indexing) plus:
//  - INTERLEAVED step schedule: MFMA(0);MFMA(1);EPI(0);MFMA(2);EPI(1);
//    MFMA(3);EPI(2);EPI(3). Epilogue VALU/trans issues while the next
//    tile's MFMA chains run in the matrix pipe (v11 was phase-serial:
//    2800 VALU + 2030 MFMA + 1700 sync = 6550 cyc/step, no overlap).
//  - pair-rcp gates: rp = rcp((1+ez)(1+en)); z = rp*pn; sig_n = rp*pz
//    -> 5 trans/h instead of 6 (trans pipe is the binding resource).
// Workspace: [0,786432) U^T bf16 [a][n(384)][kk(256)]; then finals f32 [a][b][hh].

#define B_ 128
#define N_ 32
#define H_ 128
#define TH 384
#define KK 256

#define HBF_PLANE 4224   // 33 slots * 128 B (one 32-k plane)
#define HBF_BUF   16896  // 4 planes
#define XD_STEP   256    // 32 rows * float2

typedef short bf16x8 __attribute__((ext_vector_type(8)));
typedef float f32x4 __attribute__((ext_vector_type(4)));

__device__ inline ushort f2bf(float f) {  // round-to-nearest (ties away)
    return (ushort)((__float_as_uint(f) + 0x8000u) >> 16);
}
__device__ inline ushort f2bf_rne(float f) {
    unsigned u = __float_as_uint(f);
    return (ushort)((u + 0x7FFFu + ((u >> 16) & 1u)) >> 16);
}

#define NL2E -1.44269504088896f

// ---- U1,U2 (f32, [a][k][n]) -> U^T bf16 [a][n][kk], kk = mat*128 + k ----
__global__ void conv_u(const float* __restrict__ U1, const float* __restrict__ U2,
                       ushort* __restrict__ ubf) {
    __shared__ float t[32][33];
    int bx = blockIdx.x;
    int amat = bx / 48, tile = bx % 48;
    int kt = tile / 12, ntl = tile % 12;
    int a = amat >> 1, mat = amat & 1;
    int kk0 = kt * 32, n0 = ntl * 32;
    int tx = threadIdx.x, ty = threadIdx.y;
    const float* U = mat ? U2 : U1;
#pragma unroll
    for (int r = 0; r < 4; r++)
        t[ty + r * 8][tx] = U[(a * H_ + kk0 + ty + r * 8) * TH + n0 + tx];
    __syncthreads();
#pragma unroll
    for (int r = 0; r < 4; r++) {
        int n = n0 + ty + r * 8;
        int kkl = kk0 + tx;
        ubf[(a * TH + n) * KK + mat * H_ + kkl] = f2bf_rne(t[tx][ty + r * 8]);
    }
}

// ---- persistent block-resident scan: 256 blocks x 512 threads (8 waves) ----
__global__ __launch_bounds__(512, 2) void scan_all(
    const float* __restrict__ x, const float* __restrict__ Wx,
    const float* __restrict__ bvec, const ushort* __restrict__ ubf,
    float* __restrict__ finals) {

    __shared__ __align__(16) char hbf_c[2 * HBF_BUF];    // 33792 B
    __shared__ __align__(16) char xd_c[63 * XD_STEP];    // 16128 B

    int bx = blockIdx.x;
    int a = bx >> 6, chunk = bx & 63;
    int tid = threadIdx.x;
    int lane = tid & 63, wn = tid >> 6;  // wn in [0,8): 16 hh-cols x 3 gates
    int l16 = lane & 15, lg = lane >> 4;

    for (int idx = tid; idx < (2 * HBF_BUF) / 4; idx += 512) ((unsigned*)hbf_c)[idx] = 0u;
    for (int idx = tid; idx < (63 * XD_STEP) / 4; idx += 512) ((unsigned*)xd_c)[idx] = 0u;
    __syncthreads();

    // x -> diagonal-major LDS: xd[d][i] = {x_b0(i,d-i), x_b1(i,d-i)}
    const float* xg = x + (chunk * 2) * (N_ * N_);
    for (int cell = tid; cell < 1024; cell += 512) {
        int i = cell >> 5, j = cell & 31;
        int ri = (a & 1) ? (31 - i) : i;
        int cj = (a & 2) ? (31 - j) : j;
        float v0 = xg[ri * 32 + cj];
        float v1 = xg[1024 + ri * 32 + cj];
        *(float2*)(xd_c + (i + j) * XD_STEP + i * 8) = make_float2(v0, v1);
    }

    // persistent U^T fragments (96 regs; unified VGPR/AGPR file)
    const ushort* ub = ubf + a * (TH * KK);
    bf16x8 Bf[3][8];
#pragma unroll
    for (int p = 0; p < 3; p++) {
        int n = p * H_ + wn * 16 + l16;
#pragma unroll
        for (int ks = 0; ks < 8; ks++) {
            Bf[p][ks] = *(const bf16x8*)(ub + n * KK + ks * 32 + lg * 8);
            asm volatile("" : "+v"(Bf[p][ks]));
        }
    }

    int hh = wn * 16 + l16;
    float wxp[3], bsp[3];
    {
        float wr = Wx[a * TH + hh], br = bvec[a * TH + hh];
        float wz = Wx[a * TH + H_ + hh], bz = bvec[a * TH + H_ + hh];
        float wq = Wx[a * TH + 2 * H_ + hh], bq = bvec[a * TH + 2 * H_ + hh];
        wxp[0] = wr * NL2E; bsp[0] = br * NL2E;
        wxp[1] = wz * NL2E; bsp[1] = bz * NL2E;
        wxp[2] = wq;        bsp[2] = bq;
    }

    // loop-invariant LDS addresses (A-row m = mt*16+l16 -> cell m>>1, bl m&1)
    int ciA = l16 >> 1, blA = l16 & 1;
    int aT[4], aL[4], wb[4][2][2];
#pragma unroll
    for (int mt = 0; mt < 4; mt++) {
        int st = mt * 8 + ciA;  // top slot
        aT[mt] = st * 128 + ((blA * 64 + lg * 16) ^ ((st & 7) << 4));
        int sl = st + 1;        // left slot
        aL[mt] = sl * 128 + ((blA * 64 + lg * 16) ^ ((sl & 7) << 4));
#pragma unroll
        for (int p2 = 0; p2 < 2; p2++) {
            int sw = mt * 8 + lg * 2 + p2 + 1;  // write slot (row+1)
#pragma unroll
            for (int bl = 0; bl < 2; bl++)
                wb[mt][p2][bl] = (hh >> 5) * HBF_PLANE + sw * 128 +
                                 ((bl * 64 + (hh & 31) * 2) ^ ((sw & 7) << 4));
        }
    }

    const char* xdp = xd_c + lg * 16;
    __syncthreads();

    float hp[4][2][2];  // [mt][p2][bl] latest h of row mt*8+lg*2+p2
#pragma unroll
    for (int mt = 0; mt < 4; mt++)
#pragma unroll
        for (int p2 = 0; p2 < 2; p2++)
#pragma unroll
            for (int bl = 0; bl < 2; bl++) hp[mt][p2][bl] = 0.0f;

    int slsrc = (lane - 16) & 63;

    auto step = [&](int d, auto WRC) {
        constexpr int WRB = decltype(WRC)::value;
        constexpr int RDB = WRB ^ 1;
        const char* hbr = hbf_c + RDB * HBF_BUF;
        char* hbw = hbf_c + WRB * HBF_BUF;

        // neighbor p2=1 prev-h, pulled before any update this step
        float sh[4][2];
#pragma unroll
        for (int mt = 0; mt < 4; mt++)
#pragma unroll
            for (int bl = 0; bl < 2; bl++)
                sh[mt][bl] = __shfl(hp[mt][1][bl], slsrc, 64);

        bool gm[4];
        f32x4 xv[4];
#pragma unroll
        for (int mt = 0; mt < 4; mt++) {
            gm[mt] = (d >= mt * 8) && (d <= mt * 8 + 38);  // wave-uniform window
            if (gm[mt]) xv[mt] = *(const f32x4*)(xdp + WRB * 256 + mt * 64);
        }

        f32x4 acc[4][3];
        const f32x4 z4 = {0.0f, 0.0f, 0.0f, 0.0f};

        auto do_mfma = [&](int mt) {
            bf16x8 af[8];
#pragma unroll
            for (int ks = 0; ks < 4; ks++) {
                af[ks] = *(const bf16x8*)(hbr + ks * HBF_PLANE + aT[mt]);
                af[ks + 4] = *(const bf16x8*)(hbr + ks * HBF_PLANE + aL[mt]);
            }
#pragma unroll
            for (int ks = 0; ks < 4; ks++)
#pragma unroll
                for (int p = 0; p < 3; p++)
                    acc[mt][p] = __builtin_amdgcn_mfma_f32_16x16x32_bf16(
                        af[ks], Bf[p][ks], (ks == 0) ? z4 : acc[mt][p], 0, 0, 0);
#pragma unroll
            for (int ks = 0; ks < 4; ks++)
#pragma unroll
                for (int p = 0; p < 3; p++)
                    acc[mt][p] = __builtin_amdgcn_mfma_f32_16x16x32_bf16(
                        af[ks + 4], Bf[p][ks + 4], acc[mt][p], 0, 0, 0);
        };

        auto do_epi = [&](int mt) {
            float hv[2][2];
#pragma unroll
            for (int p2 = 0; p2 < 2; p2++)
#pragma unroll
                for (int bl = 0; bl < 2; bl++) {
                    int r = p2 * 2 + bl;
                    float xb = xv[mt][r];
                    float htop = p2 ? hp[mt][0][bl]
                                    : (lg ? sh[mt][bl]
                                          : (mt ? sh[mt - 1][bl] : 0.0f));
                    float hlft = hp[mt][p2][bl];
                    float Gr = acc[mt][0][r];
                    float Gz = acc[mt][1][r];
                    float Gn = acc[mt][2][r];
                    // r-gate (serial: needed inside tanh arg)
                    float ar = __builtin_fmaf(Gr, NL2E, __builtin_fmaf(xb, wxp[0], bsp[0]));
                    float rg = __builtin_amdgcn_rcpf(1.0f + __builtin_amdgcn_exp2f(ar));
                    // z-gate + n-gate share one rcp: rp = 1/((1+ez)(1+en))
                    float az = __builtin_fmaf(Gz, NL2E, __builtin_fmaf(xb, wxp[1], bsp[1]));
                    float ez = __builtin_amdgcn_exp2f(az);
                    float vn = __builtin_fmaf(rg, Gn, __builtin_fmaf(xb, wxp[2], bsp[2]));
                    float en = __builtin_amdgcn_exp2f(vn * (2.0f * NL2E));
                    float pz = 1.0f + ez, pn = 1.0f + en;
                    float rp = __builtin_amdgcn_rcpf(pz * pn);
                    float zg = rp * pn;                       // sigmoid(z-arg)
                    float ng = __builtin_fmaf(2.0f * rp, pz, -1.0f);  // tanh(vn)
                    float hs = htop + hlft;
                    hv[p2][bl] = __builtin_fmaf(-zg, __builtin_fmaf(-0.5f, hs, ng), ng);
                }
#pragma unroll
            for (int p2 = 0; p2 < 2; p2++)
#pragma unroll
                for (int bl = 0; bl < 2; bl++) {
                    *(ushort*)(hbw + wb[mt][p2][bl]) = f2bf(hv[p2][bl]);
                    hp[mt][p2][bl] = hv[p2][bl];
                }
        };

        // interleaved schedule: EPI(mt) overlaps MFMA(mt+1) in the other pipe
        if (gm[0]) do_mfma(0);
        if (gm[1]) do_mfma(1);
        if (gm[0]) do_epi(0);
        if (gm[2]) do_mfma(2);
        if (gm[1]) do_epi(1);
        if (gm[3]) do_mfma(3);
        if (gm[2]) do_epi(2);
        if (gm[3]) do_epi(3);

        __syncthreads();
    };

    for (int d = 0; d < 62; d += 2) {
        step(d, std::integral_constant<int, 0>{});
        step(d + 1, std::integral_constant<int, 1>{});
        xdp += 512;
    }
    step(62, std::integral_constant<int, 0>{});

    // terminal corner: row 31 = mt3/p2=1 on lg==3 lanes
    if (lg == 3) {
        finals[(a * B_ + chunk * 2) * H_ + hh] = hp[3][1][0];
        finals[(a * B_ + chunk * 2 + 1) * H_ + hh] = hp[3][1][1];
    }
}

// ---- final: concat 4 terminal h's -> logits -> log_softmax ----
__global__ void classify(const float* __restrict__ fin, const float* __restrict__ Wo,
                         const float* __restrict__ bo, float* __restrict__ out) {
    int b = blockIdx.x;
    int lane = threadIdx.x;  // 64
    float acc[10];
#pragma unroll
    for (int o = 0; o < 10; o++) acc[o] = 0.0f;
#pragma unroll
    for (int kkx = 0; kkx < 8; kkx++) {
        int k = kkx * 64 + lane;
        int a = k >> 7, hh = k & 127;
        float fh = fin[(a * B_ + b) * H_ + hh];
#pragma unroll
        for (int o = 0; o < 10; o++) acc[o] += fh * Wo[k * 10 + o];
    }
    float logits[10];
#pragma unroll
    for (int o = 0; o < 10; o++) {
        float v = acc[o];
#pragma unroll
        for (int off = 32; off; off >>= 1) v += __shfl_xor(v, off, 64);
        logits[o] = v + bo[o];
    }
    float m = logits[0];
#pragma unroll
    for (int o = 1; o < 10; o++) m = fmaxf(m, logits[o]);
    float s = 0.0f;
#pragma unroll
    for (int o = 0; o < 10; o++) s += __expf(logits[o] - m);
    float lse = m + __logf(s);
    if (lane == 0) {
#pragma unroll
        for (int o = 0; o < 10; o++) out[b * 10 + o] = logits[o] - lse;
    }
}

extern "C" void kernel_launch(void* const* d_in, const int* in_sizes, int n_in,
                              void* d_out, int out_size, void* d_ws, size_t ws_size,
                              hipStream_t stream) {
    const float* x = (const float*)d_in[0];
    const float* Wx = (const float*)d_in[1];
    const float* U1 = (const float*)d_in[2];
    const float* U2 = (const float*)d_in[3];
    const float* bv = (const float*)d_in[4];
    const float* Wo = (const float*)d_in[5];
    const float* bo = (const float*)d_in[6];
    float* out = (float*)d_out;

    char* ws = (char*)d_ws;
    ushort* ubf = (ushort*)ws;                // 786432 B
    float* finals = (float*)(ws + 786432);    // 4*128*128*4 = 256 KB

    hipLaunchKernelGGL(conv_u, dim3(384), dim3(32, 8), 0, stream, U1, U2, ubf);
    hipLaunchKernelGGL(scan_all, dim3(256), dim3(512), 0, stream, x, Wx, bv, ubf, finals);
    hipLaunchKernelGGL(classify, dim3(128), dim3(64), 0, stream, finals, Wo, bo, out);
}